// Round 1
// baseline (1526.747 us; speedup 1.0000x reference)
//
#include <hip/hip_runtime.h>
#include <math.h>

#define HW_N   147456           // 384*384
#define NCH    32
#define NBATCH 8
#define NCHUNK 128              // 1024 blocks = exactly 4 per CU, no tail
#define CP     (HW_N / NCHUNK)  // 1152 positions per block
#define TILE_P 128
#define NTILE  (CP / TILE_P)    // 9 tiles

// ---------------------------------------------------------------------------
// Phase 1: per-batch channel gram G[b][i][j] = sum_hw q[b,i,hw]*v[b,j,hw]
//          plus channel sums sq[b][c], sv[b][c].
// T14 software pipeline: regs hold tile k+1 while LDS serves tile k; global
// load latency hides under the 512-FMA compute phase instead of sitting
// serially in front of the barrier.
// ---------------------------------------------------------------------------
__global__ __launch_bounds__(256, 4) void gram_kernel(
    const float* __restrict__ q, const float* __restrict__ v,
    float* __restrict__ G, float* __restrict__ sq, float* __restrict__ sv)
{
    __shared__ float qs[NCH][130];   // stride 130: 2-way LDS alias max (free)
    __shared__ float vs[NCH][130];

    const int b     = blockIdx.y;
    const int chunk = blockIdx.x;
    const int t     = threadIdx.x;
    const int lane  = t & 63;
    const int w     = t >> 6;        // wave id 0..3
    const int ig    = lane & 7;      // i = 4*ig + ii
    const int jg    = lane >> 3;     // j = 4*jg + jj
    const int r0    = t >> 5;        // staging rows r0, r0+8, r0+16, r0+24
    const int c0    = t & 31;        // staging float4 column

    // per-thread staging base: row r0, column 4*c0
    const float* qb = q + (size_t)b * NCH * HW_N + (size_t)r0 * HW_N + 4 * c0;
    const float* vb = v + (size_t)b * NCH * HW_N + (size_t)r0 * HW_N + 4 * c0;

    float acc[4][4];
#pragma unroll
    for (int ii = 0; ii < 4; ++ii)
#pragma unroll
        for (int jj = 0; jj < 4; ++jj) acc[ii][jj] = 0.f;

    float sumq[4] = {0.f, 0.f, 0.f, 0.f};
    float sumv[4] = {0.f, 0.f, 0.f, 0.f};

    const int p_base = chunk * CP;

    // ---- prologue: load tile 0 into registers ----
    float4 pq[4], pv[4];
#pragma unroll
    for (int k = 0; k < 4; ++k) {
        const size_t off = (size_t)(8 * k) * HW_N + p_base;
        pq[k] = *(const float4*)(qb + off);
        pv[k] = *(const float4*)(vb + off);
    }

    for (int tile = 0; tile < NTILE; ++tile) {
        // ---- commit prefetched tile to LDS; fold channel sums ----
#pragma unroll
        for (int k = 0; k < 4; ++k) {
            const int r = r0 + 8 * k;
            *(float2*)&qs[r][4 * c0]     = make_float2(pq[k].x, pq[k].y);
            *(float2*)&qs[r][4 * c0 + 2] = make_float2(pq[k].z, pq[k].w);
            *(float2*)&vs[r][4 * c0]     = make_float2(pv[k].x, pv[k].y);
            *(float2*)&vs[r][4 * c0 + 2] = make_float2(pv[k].z, pv[k].w);
            sumq[k] += pq[k].x + pq[k].y + pq[k].z + pq[k].w;
            sumv[k] += pv[k].x + pv[k].y + pv[k].z + pv[k].w;
        }
        __syncthreads();

        // ---- issue next tile's loads; latency hides under compute below ----
        float4 nq[4], nv[4];
        const bool more = (tile + 1 < NTILE);
        if (more) {
            const int p0 = p_base + (tile + 1) * TILE_P;
#pragma unroll
            for (int k = 0; k < 4; ++k) {
                const size_t off = (size_t)(8 * k) * HW_N + p0;
                nq[k] = *(const float4*)(qb + off);
                nv[k] = *(const float4*)(vb + off);
            }
        }

        // ---- compute: wave w owns positions [w*32, w*32+32) ----
        const int pw = w * 32;
#pragma unroll
        for (int p2 = 0; p2 < 32; p2 += 2) {
            float2 qv[4], vv[4];
#pragma unroll
            for (int ii = 0; ii < 4; ++ii)
                qv[ii] = *(const float2*)&qs[4 * ig + ii][pw + p2];
#pragma unroll
            for (int jj = 0; jj < 4; ++jj)
                vv[jj] = *(const float2*)&vs[4 * jg + jj][pw + p2];
#pragma unroll
            for (int ii = 0; ii < 4; ++ii)
#pragma unroll
                for (int jj = 0; jj < 4; ++jj)
                    acc[ii][jj] += qv[ii].x * vv[jj].x + qv[ii].y * vv[jj].y;
        }
        __syncthreads();   // drains vmcnt too -- after compute, so it's free

        if (more) {
#pragma unroll
            for (int k = 0; k < 4; ++k) { pq[k] = nq[k]; pv[k] = nv[k]; }
        }
    }

    // ---- cross-wave reduction via LDS (reuse qs for G, vs for sums) ----
    float* red  = &qs[0][0];   // 4*1024 <= 32*130
    float* redv = &vs[0][0];   // 2*1024 <= 32*130
#pragma unroll
    for (int ii = 0; ii < 4; ++ii)
#pragma unroll
        for (int jj = 0; jj < 4; ++jj) {
            int i = 4 * ig + ii, j = 4 * jg + jj;
            red[w * 1024 + i * 32 + j] = acc[ii][jj];
        }
#pragma unroll
    for (int k = 0; k < 4; ++k) {
        int f = t + k * 256;
        redv[f]        = sumq[k];
        redv[1024 + f] = sumv[k];
    }
    __syncthreads();
#pragma unroll
    for (int k = 0; k < 4; ++k) {
        int pr = t + k * 256;
        float s = red[pr] + red[1024 + pr] + red[2048 + pr] + red[3072 + pr];
        atomicAdd(&G[b * 1024 + pr], s);
    }
    if (t < 32) {
        float s1 = 0.f, s2 = 0.f;
#pragma unroll
        for (int c = 0; c < 32; ++c) {
            s1 += redv[t * 32 + c];
            s2 += redv[1024 + t * 32 + c];
        }
        atomicAdd(&sq[b * 32 + t], s1);
        atomicAdd(&sv[b * 32 + t], s2);
    }
}

// ---------------------------------------------------------------------------
// Phase 2: logits -> softmax -> M = wo@S@wa, e = wo@(S@ba) + bo. Tiny.
// ---------------------------------------------------------------------------
__global__ __launch_bounds__(1024) void attn_kernel(
    const float* __restrict__ G, const float* __restrict__ sq, const float* __restrict__ sv,
    const float* __restrict__ wa, const float* __restrict__ ba,
    const float* __restrict__ wb, const float* __restrict__ bb,
    const float* __restrict__ wc, const float* __restrict__ bc,
    const float* __restrict__ wo, const float* __restrict__ bo,
    float* __restrict__ M, float* __restrict__ e)
{
    const int b = blockIdx.x;
    const int t = threadIdx.x;
    const int i = t >> 5;
    const int j = t & 31;

    __shared__ float Gs[32][33], T[32][33], Ss[32][33], sba[32];

    Gs[i][j] = G[b * 1024 + i * 32 + j];
    __syncthreads();

    float acc = 0.f;
#pragma unroll
    for (int c = 0; c < 32; ++c) acc += wc[i * 32 + c] * Gs[c][j];
    T[i][j] = acc;
    __syncthreads();

    float L = 0.f;
#pragma unroll
    for (int d = 0; d < 32; ++d) L += T[i][d] * wb[j * 32 + d];
    float sqw = 0.f, svw = 0.f;
#pragma unroll
    for (int c = 0; c < 32; ++c) {
        sqw += wc[i * 32 + c] * sq[b * 32 + c];
        svw += wb[j * 32 + c] * sv[b * 32 + c];
    }
    L += bc[i] * svw + bb[j] * sqw + bc[i] * bb[j] * (float)HW_N;

    float m = L;
#pragma unroll
    for (int off = 16; off >= 1; off >>= 1) m = fmaxf(m, __shfl_xor(m, off));
    float ex = __expf(L - m);
    float s = ex;
#pragma unroll
    for (int off = 16; off >= 1; off >>= 1) s += __shfl_xor(s, off);
    float S = ex / s;
    Ss[i][j] = S;

    float p = S * ba[j];
#pragma unroll
    for (int off = 16; off >= 1; off >>= 1) p += __shfl_xor(p, off);
    if (j == 0) sba[i] = p;
    __syncthreads();

    float acc2 = 0.f;
#pragma unroll
    for (int jj = 0; jj < 32; ++jj) acc2 += Ss[i][jj] * wa[jj * 32 + j];
    T[i][j] = acc2;
    __syncthreads();

    float acc3 = 0.f;
#pragma unroll
    for (int ii = 0; ii < 32; ++ii) acc3 += wo[i * 32 + ii] * T[ii][j];
    M[b * 1024 + i * 32 + j] = acc3;

    if (j == 0) {
        float ee = bo[i];
#pragma unroll
        for (int ii = 0; ii < 32; ++ii) ee += wo[i * 32 + ii] * sba[ii];
        e[b * 32 + i] = ee;
    }
}

// ---------------------------------------------------------------------------
// Phase 3: out[b,o,p] = sum_d M[b][o][d]*v[b,d,p] + e[b][o] + v[b,o,p]
// Same T14 pipeline: prefetch the next v-tile into registers during compute.
// ---------------------------------------------------------------------------
__global__ __launch_bounds__(256, 4) void out_kernel(
    const float* __restrict__ v, const float* __restrict__ M,
    const float* __restrict__ e, float* __restrict__ out)
{
    __shared__ float vs[NCH][130];
    __shared__ float Ms[32][33];
    __shared__ float es[32];

    const int b  = blockIdx.y;
    const int t  = threadIdx.x;
    const int pg = t & 31;
    const int oq = t >> 5;
    const int r0 = t >> 5;
    const int c0 = t & 31;

    const float* vb = v + (size_t)b * NCH * HW_N + (size_t)r0 * HW_N + 4 * c0;

#pragma unroll
    for (int k = 0; k < 4; ++k) {
        int f = t + k * 256;
        Ms[f >> 5][f & 31] = M[b * 1024 + f];
    }
    if (t < 32) es[t] = e[b * 32 + t];

    const int p_base = blockIdx.x * CP;

    // ---- prologue: load tile 0 ----
    float4 pvv[4];
#pragma unroll
    for (int k = 0; k < 4; ++k)
        pvv[k] = *(const float4*)(vb + (size_t)(8 * k) * HW_N + p_base);

    for (int tile = 0; tile < NTILE; ++tile) {
        // ---- commit prefetched tile to LDS ----
#pragma unroll
        for (int k = 0; k < 4; ++k) {
            const int r = r0 + 8 * k;
            *(float2*)&vs[r][4 * c0]     = make_float2(pvv[k].x, pvv[k].y);
            *(float2*)&vs[r][4 * c0 + 2] = make_float2(pvv[k].z, pvv[k].w);
        }
        __syncthreads();

        // ---- issue next tile's loads ----
        float4 nvv[4];
        const bool more = (tile + 1 < NTILE);
        if (more) {
            const int pn = p_base + (tile + 1) * TILE_P;
#pragma unroll
            for (int k = 0; k < 4; ++k)
                nvv[k] = *(const float4*)(vb + (size_t)(8 * k) * HW_N + pn);
        }

        // ---- compute current tile from LDS ----
        float acc[4][4];
#pragma unroll
        for (int oo = 0; oo < 4; ++oo)
#pragma unroll
            for (int pp = 0; pp < 4; ++pp) acc[oo][pp] = 0.f;

#pragma unroll
        for (int d = 0; d < 32; ++d) {
            float2 va = *(const float2*)&vs[d][2 * pg];
            float2 vc = *(const float2*)&vs[d][2 * pg + 64];
#pragma unroll
            for (int oo = 0; oo < 4; ++oo) {
                float mm = Ms[4 * oq + oo][d];
                acc[oo][0] += mm * va.x;
                acc[oo][1] += mm * va.y;
                acc[oo][2] += mm * vc.x;
                acc[oo][3] += mm * vc.y;
            }
        }

        const int p0 = p_base + tile * TILE_P;
#pragma unroll
        for (int oo = 0; oo < 4; ++oo) {
            int o = 4 * oq + oo;
            float eo = es[o];
            float w0 = acc[oo][0] + eo + vs[o][2 * pg];
            float w1 = acc[oo][1] + eo + vs[o][2 * pg + 1];
            float w2 = acc[oo][2] + eo + vs[o][2 * pg + 64];
            float w3 = acc[oo][3] + eo + vs[o][2 * pg + 65];
            size_t base = ((size_t)(b * NCH + o)) * HW_N + p0;
            *(float2*)(out + base + 2 * pg)      = make_float2(w0, w1);
            *(float2*)(out + base + 2 * pg + 64) = make_float2(w2, w3);
        }
        __syncthreads();

        if (more) {
#pragma unroll
            for (int k = 0; k < 4; ++k) pvv[k] = nvv[k];
        }
    }
}

// ---------------------------------------------------------------------------
extern "C" void kernel_launch(void* const* d_in, const int* in_sizes, int n_in,
                              void* d_out, int out_size, void* d_ws, size_t ws_size,
                              hipStream_t stream) {
    const float* q  = (const float*)d_in[0];
    const float* v  = (const float*)d_in[1];
    const float* wa = (const float*)d_in[2];
    const float* ba = (const float*)d_in[3];
    const float* wb = (const float*)d_in[4];
    const float* bb = (const float*)d_in[5];
    const float* wc = (const float*)d_in[6];
    const float* bc = (const float*)d_in[7];
    const float* wo = (const float*)d_in[8];
    const float* bo = (const float*)d_in[9];
    float* out = (float*)d_out;

    float* G  = (float*)d_ws;            // 8*1024
    float* sq = G + NBATCH * 1024;       // 8*32
    float* sv = sq + NBATCH * 32;        // 8*32
    float* M  = sv + NBATCH * 32;        // 8*1024
    float* e  = M + NBATCH * 1024;       // 8*32

    // ws is poisoned 0xAA before every launch -> zero the accumulators.
    hipMemsetAsync(d_ws, 0, (size_t)(NBATCH * 1024 + 2 * NBATCH * 32) * sizeof(float), stream);

    gram_kernel<<<dim3(NCHUNK, NBATCH), 256, 0, stream>>>(q, v, G, sq, sv);
    attn_kernel<<<NBATCH, 1024, 0, stream>>>(G, sq, sv, wa, ba, wb, bb, wc, bc, wo, bo, M, e);
    out_kernel<<<dim3(NCHUNK, NBATCH), 256, 0, stream>>>(v, M, e, out);
}

// Round 2
// 465.107 us; speedup vs baseline: 3.2826x; 3.2826x over previous
//
#include <hip/hip_runtime.h>
#include <math.h>

#define HW_N   147456           // 384*384
#define NCH    32
#define NBATCH 8
#define NCHUNK 128              // 1024 blocks
#define CP     (HW_N / NCHUNK)  // 1152 positions per block
#define TP1    64               // gram tile width (positions)
#define NT1    (CP / TP1)       // 18
#define TP3    128              // out tile width
#define NT3    (CP / TP3)       // 9

// Async global->LDS DMA, 16 B per lane, LDS dest = wave-uniform base + lane*16.
#define GL2LDS16(g, l)                                                            \
    __builtin_amdgcn_global_load_lds(                                             \
        (const __attribute__((address_space(1))) void*)(g),                       \
        (__attribute__((address_space(3))) void*)(l), 16, 0, 0)

// ---------------------------------------------------------------------------
// Phase 1: G[b][i][j] = sum_hw q[b,i,hw]*v[b,j,hw]; sq/sv channel sums.
// T3 2-phase: global_load_lds double-buffer (zero VGPR staging cost).
// LDS layout is linear [32][64] (required by global_load_lds); bank conflicts
// avoided by XOR-swizzling the GLOBAL source chunk (slot s of row r holds
// global float4-chunk s ^ ((r>>2)&7)), and reading with the same XOR.
// ---------------------------------------------------------------------------
__global__ __launch_bounds__(256, 4) void gram_kernel(
    const float* __restrict__ q, const float* __restrict__ v,
    float* __restrict__ G, float* __restrict__ sq, float* __restrict__ sv)
{
    __shared__ float qs[2][NCH][TP1];   // 16 KB
    __shared__ float vs[2][NCH][TP1];   // 16 KB

    const int b     = blockIdx.y;
    const int chunk = blockIdx.x;
    const int t     = threadIdx.x;
    const int lane  = t & 63;
    const int w     = t >> 6;        // wave id 0..3
    const int ig    = lane & 7;      // i = 4*ig + ii  (row>>2 == ig)
    const int jg    = lane >> 3;     // j = 4*jg + jj

    // staging geometry: call k covers rows 16k + (t>>4), slot t&15
    const int sr0 = t >> 4;          // 0..15
    const int ss  = t & 15;
    const int cg0 = ss ^ ((sr0 >> 2) & 7);
    const int cg1 = ss ^ (((sr0 >> 2) + 4) & 7);   // rows +16: (r>>2)+4

    const float* qb = q + (size_t)b * NCH * HW_N;
    const float* vb = v + (size_t)b * NCH * HW_N;
    const int p_base = chunk * CP;

    const float* gq0 = qb + (size_t)sr0 * HW_N        + p_base + 4 * cg0;
    const float* gq1 = qb + (size_t)(sr0 + 16) * HW_N + p_base + 4 * cg1;
    const float* gv0 = vb + (size_t)sr0 * HW_N        + p_base + 4 * cg0;
    const float* gv1 = vb + (size_t)(sr0 + 16) * HW_N + p_base + 4 * cg1;

    float acc[4][4];
#pragma unroll
    for (int ii = 0; ii < 4; ++ii)
#pragma unroll
        for (int jj = 0; jj < 4; ++jj) acc[ii][jj] = 0.f;
    float sqa = 0.f, sqb = 0.f, sva = 0.f, svb = 0.f;

    // prologue: stage tile 0 into buffer 0
    GL2LDS16(gq0, &qs[0][4 * w][0]);
    GL2LDS16(gq1, &qs[0][16 + 4 * w][0]);
    GL2LDS16(gv0, &vs[0][4 * w][0]);
    GL2LDS16(gv1, &vs[0][16 + 4 * w][0]);
    __syncthreads();

    int cur = 0;
    for (int tile = 0; tile < NT1; ++tile) {
        // issue next tile's DMA first; it completes during compute below
        if (tile + 1 < NT1) {
            const int off = (tile + 1) * TP1;
            GL2LDS16(gq0 + off, &qs[cur ^ 1][4 * w][0]);
            GL2LDS16(gq1 + off, &qs[cur ^ 1][16 + 4 * w][0]);
            GL2LDS16(gv0 + off, &vs[cur ^ 1][4 * w][0]);
            GL2LDS16(gv1 + off, &vs[cur ^ 1][16 + 4 * w][0]);
        }

        // compute: wave w owns positions [16w, 16w+16) => chunks 4w..4w+3
#pragma unroll
        for (int s = 0; s < 4; ++s) {
            const int c = 4 * w + s;
            float4 qf[4], vf[4];
#pragma unroll
            for (int ii = 0; ii < 4; ++ii)
                qf[ii] = *(const float4*)&qs[cur][4 * ig + ii][(c ^ ig) << 2];
#pragma unroll
            for (int jj = 0; jj < 4; ++jj)
                vf[jj] = *(const float4*)&vs[cur][4 * jg + jj][(c ^ jg) << 2];
#pragma unroll
            for (int ii = 0; ii < 4; ++ii)
#pragma unroll
                for (int jj = 0; jj < 4; ++jj)
                    acc[ii][jj] += qf[ii].x * vf[jj].x + qf[ii].y * vf[jj].y
                                 + qf[ii].z * vf[jj].z + qf[ii].w * vf[jj].w;
        }

        // channel sums: contiguous sweep (swizzle-invariant; rows preserved).
        // thread t always covers floats [4t,4t+4) -> row sr0, and +1024 -> row sr0+16
        {
            const float* qflat = &qs[cur][0][0];
            const float* vflat = &vs[cur][0][0];
            float4 x0 = *(const float4*)(qflat + 4 * t);
            float4 x1 = *(const float4*)(qflat + 4 * t + 1024);
            float4 y0 = *(const float4*)(vflat + 4 * t);
            float4 y1 = *(const float4*)(vflat + 4 * t + 1024);
            sqa += x0.x + x0.y + x0.z + x0.w;
            sqb += x1.x + x1.y + x1.z + x1.w;
            sva += y0.x + y0.y + y0.z + y0.w;
            svb += y1.x + y1.y + y1.z + y1.w;
        }
        __syncthreads();   // vmcnt(0)+barrier: next tile's DMA has landed
        cur ^= 1;
    }

    // ---- channel-sum reduction: 16 threads share row sr0 (same wave, xor<=8) ----
#pragma unroll
    for (int off = 1; off < 16; off <<= 1) {
        sqa += __shfl_xor(sqa, off);
        sqb += __shfl_xor(sqb, off);
        sva += __shfl_xor(sva, off);
        svb += __shfl_xor(svb, off);
    }
    if ((t & 15) == 0) {
        atomicAdd(&sq[b * 32 + sr0],      sqa);
        atomicAdd(&sq[b * 32 + sr0 + 16], sqb);
        atomicAdd(&sv[b * 32 + sr0],      sva);
        atomicAdd(&sv[b * 32 + sr0 + 16], svb);
    }

    // ---- cross-wave G reduction (reuse qs: exactly 4096 floats) ----
    float* red = &qs[0][0][0];
#pragma unroll
    for (int ii = 0; ii < 4; ++ii)
#pragma unroll
        for (int jj = 0; jj < 4; ++jj)
            red[w * 1024 + (4 * ig + ii) * 32 + (4 * jg + jj)] = acc[ii][jj];
    __syncthreads();
#pragma unroll
    for (int k = 0; k < 4; ++k) {
        int pr = t + k * 256;
        float s2 = red[pr] + red[1024 + pr] + red[2048 + pr] + red[3072 + pr];
        atomicAdd(&G[b * 1024 + pr], s2);
    }
}

// ---------------------------------------------------------------------------
// Phase 2: logits -> softmax -> M = wo@S@wa, e = wo@(S@ba) + bo. Tiny.
// ---------------------------------------------------------------------------
__global__ __launch_bounds__(1024) void attn_kernel(
    const float* __restrict__ G, const float* __restrict__ sq, const float* __restrict__ sv,
    const float* __restrict__ wa, const float* __restrict__ ba,
    const float* __restrict__ wb, const float* __restrict__ bb,
    const float* __restrict__ wc, const float* __restrict__ bc,
    const float* __restrict__ wo, const float* __restrict__ bo,
    float* __restrict__ M, float* __restrict__ e)
{
    const int b = blockIdx.x;
    const int t = threadIdx.x;
    const int i = t >> 5;
    const int j = t & 31;

    __shared__ float Gs[32][33], T[32][33], Ss[32][33], sba[32];

    Gs[i][j] = G[b * 1024 + i * 32 + j];
    __syncthreads();

    float acc = 0.f;
#pragma unroll
    for (int c = 0; c < 32; ++c) acc += wc[i * 32 + c] * Gs[c][j];
    T[i][j] = acc;
    __syncthreads();

    float L = 0.f;
#pragma unroll
    for (int d = 0; d < 32; ++d) L += T[i][d] * wb[j * 32 + d];
    float sqw = 0.f, svw = 0.f;
#pragma unroll
    for (int c = 0; c < 32; ++c) {
        sqw += wc[i * 32 + c] * sq[b * 32 + c];
        svw += wb[j * 32 + c] * sv[b * 32 + c];
    }
    L += bc[i] * svw + bb[j] * sqw + bc[i] * bb[j] * (float)HW_N;

    float m = L;
#pragma unroll
    for (int off = 16; off >= 1; off >>= 1) m = fmaxf(m, __shfl_xor(m, off));
    float ex = __expf(L - m);
    float s = ex;
#pragma unroll
    for (int off = 16; off >= 1; off >>= 1) s += __shfl_xor(s, off);
    float S = ex / s;
    Ss[i][j] = S;

    float p = S * ba[j];
#pragma unroll
    for (int off = 16; off >= 1; off >>= 1) p += __shfl_xor(p, off);
    if (j == 0) sba[i] = p;
    __syncthreads();

    float acc2 = 0.f;
#pragma unroll
    for (int jj = 0; jj < 32; ++jj) acc2 += Ss[i][jj] * wa[jj * 32 + j];
    T[i][j] = acc2;
    __syncthreads();

    float acc3 = 0.f;
#pragma unroll
    for (int ii = 0; ii < 32; ++ii) acc3 += wo[i * 32 + ii] * T[ii][j];
    M[b * 1024 + i * 32 + j] = acc3;

    if (j == 0) {
        float ee = bo[i];
#pragma unroll
        for (int ii = 0; ii < 32; ++ii) ee += wo[i * 32 + ii] * sba[ii];
        e[b * 32 + i] = ee;
    }
}

// ---------------------------------------------------------------------------
// Phase 3: out[b,o,p] = sum_d M[b][o][d]*v[b,d,p] + e[b][o] + v[b,o,p]
// Same T3 2-phase global_load_lds dbuf + source-side XOR swizzle.
// M is transposed once into LDS (MsT[d][o]) so the inner loop is
// 2x ds_read_b128 + 16 FMA per d.
// ---------------------------------------------------------------------------
__global__ __launch_bounds__(256, 4) void out_kernel(
    const float* __restrict__ v, const float* __restrict__ M,
    const float* __restrict__ e, float* __restrict__ out)
{
    __shared__ float vsd[2][NCH][TP3];   // 32 KB
    __shared__ float MsT[32][36];        // MsT[d][o] = M[o][d]; stride 36 keeps 16B align
    __shared__ float es[32];

    const int b  = blockIdx.y;
    const int t  = threadIdx.x;
    const int w  = t >> 6;
    const int pg = t & 31;           // thread's float4-chunk of positions
    const int oq = t >> 5;           // 0..7: output rows 4*oq..4*oq+3

    // staging geometry: call k covers rows 8k + (t>>5), slot t&31
    const int sr = t >> 5;
    const int ss = t & 31;

    const float* vb = v + (size_t)b * NCH * HW_N;
    const int p_base = blockIdx.x * CP;

    const float* gv0 = vb + (size_t)(sr)      * HW_N + p_base + 4 * (ss ^ (((sr)      >> 2) & 7));
    const float* gv1 = vb + (size_t)(sr + 8)  * HW_N + p_base + 4 * (ss ^ (((sr + 8)  >> 2) & 7));
    const float* gv2 = vb + (size_t)(sr + 16) * HW_N + p_base + 4 * (ss ^ (((sr + 16) >> 2) & 7));
    const float* gv3 = vb + (size_t)(sr + 24) * HW_N + p_base + 4 * (ss ^ (((sr + 24) >> 2) & 7));

    // prologue: stage tile 0; transpose M; load e
    GL2LDS16(gv0, &vsd[0][2 * w][0]);
    GL2LDS16(gv1, &vsd[0][8 + 2 * w][0]);
    GL2LDS16(gv2, &vsd[0][16 + 2 * w][0]);
    GL2LDS16(gv3, &vsd[0][24 + 2 * w][0]);
#pragma unroll
    for (int k = 0; k < 4; ++k) {
        int f = t + 256 * k;
        MsT[f & 31][f >> 5] = M[b * 1024 + f];
    }
    if (t < 32) es[t] = e[b * 32 + t];
    __syncthreads();

    int cur = 0;
    for (int tile = 0; tile < NT3; ++tile) {
        if (tile + 1 < NT3) {
            const int off = (tile + 1) * TP3;
            GL2LDS16(gv0 + off, &vsd[cur ^ 1][2 * w][0]);
            GL2LDS16(gv1 + off, &vsd[cur ^ 1][8 + 2 * w][0]);
            GL2LDS16(gv2 + off, &vsd[cur ^ 1][16 + 2 * w][0]);
            GL2LDS16(gv3 + off, &vsd[cur ^ 1][24 + 2 * w][0]);
        }

        float4 a[4];
#pragma unroll
        for (int oo = 0; oo < 4; ++oo) a[oo] = make_float4(0.f, 0.f, 0.f, 0.f);

#pragma unroll
        for (int d = 0; d < 32; ++d) {
            float4 vv = *(const float4*)&vsd[cur][d][(pg ^ ((d >> 2) & 7)) << 2];
            float4 m4 = *(const float4*)&MsT[d][4 * oq];
            a[0].x += m4.x * vv.x; a[0].y += m4.x * vv.y; a[0].z += m4.x * vv.z; a[0].w += m4.x * vv.w;
            a[1].x += m4.y * vv.x; a[1].y += m4.y * vv.y; a[1].z += m4.y * vv.z; a[1].w += m4.y * vv.w;
            a[2].x += m4.z * vv.x; a[2].y += m4.z * vv.y; a[2].z += m4.z * vv.z; a[2].w += m4.z * vv.w;
            a[3].x += m4.w * vv.x; a[3].y += m4.w * vv.y; a[3].z += m4.w * vv.z; a[3].w += m4.w * vv.w;
        }

        const int p0 = p_base + tile * TP3;
#pragma unroll
        for (int oo = 0; oo < 4; ++oo) {
            const int o = 4 * oq + oo;
            float4 rv = *(const float4*)&vsd[cur][o][(pg ^ ((o >> 2) & 7)) << 2];
            float eo = es[o];
            float4 r;
            r.x = a[oo].x + eo + rv.x;
            r.y = a[oo].y + eo + rv.y;
            r.z = a[oo].z + eo + rv.z;
            r.w = a[oo].w + eo + rv.w;
            *(float4*)(out + ((size_t)(b * NCH + o)) * HW_N + p0 + 4 * pg) = r;
        }
        __syncthreads();
        cur ^= 1;
    }
}

// ---------------------------------------------------------------------------
extern "C" void kernel_launch(void* const* d_in, const int* in_sizes, int n_in,
                              void* d_out, int out_size, void* d_ws, size_t ws_size,
                              hipStream_t stream) {
    const float* q  = (const float*)d_in[0];
    const float* v  = (const float*)d_in[1];
    const float* wa = (const float*)d_in[2];
    const float* ba = (const float*)d_in[3];
    const float* wb = (const float*)d_in[4];
    const float* bb = (const float*)d_in[5];
    const float* wc = (const float*)d_in[6];
    const float* bc = (const float*)d_in[7];
    const float* wo = (const float*)d_in[8];
    const float* bo = (const float*)d_in[9];
    float* out = (float*)d_out;

    float* G  = (float*)d_ws;            // 8*1024
    float* sq = G + NBATCH * 1024;       // 8*32
    float* sv = sq + NBATCH * 32;        // 8*32
    float* M  = sv + NBATCH * 32;        // 8*1024
    float* e  = M + NBATCH * 1024;       // 8*32

    // ws is poisoned 0xAA before every launch -> zero the accumulators.
    hipMemsetAsync(d_ws, 0, (size_t)(NBATCH * 1024 + 2 * NBATCH * 32) * sizeof(float), stream);

    gram_kernel<<<dim3(NCHUNK, NBATCH), 256, 0, stream>>>(q, v, G, sq, sv);
    attn_kernel<<<NBATCH, 1024, 0, stream>>>(G, sq, sv, wa, ba, wb, bb, wc, bc, wo, bo, M, e);
    out_kernel<<<dim3(NCHUNK, NBATCH), 256, 0, stream>>>(v, M, e, out);
}